// Round 7
// baseline (114.306 us; speedup 1.0000x reference)
//
#include <hip/hip_runtime.h>
#include <math.h>
#include <type_traits>

// SDE Euler-Maruyama path generator — affine-scan decomposition, v6.
//   step:  x' = S_k x + t_k,  S_k = I + dt*A + diag(dW_k)*C,  t_k = dt*b + dW_k*d
// Chunk grid ALIGNED to cache lines: CL=48 steps -> 576 B = 9 full 64B lines
// per (path, chunk). Each replay wave writes states [48c, 48c+48): boundary
// state first, then 47 computed states -> zero partial-line seams, no write
// amplification (round-1 evidence: per-thread row streaming = 1.00x WRITE).
// Phase 1: compose 52 uniform 48-step chunk affines        [B*52 threads]
// Phase 2: scan 52 affines, write 53 boundaries into trans [B threads]
// Phase 3: replay; register-only, immediate dwordx3 stores [B*53 threads]

constexpr int B_N  = 4096;
constexpr int T_N  = 2500;
constexpr int CL   = 48;            // chunk length (mult of 16 -> 64B-aligned regions)
constexpr int NFC  = T_N / CL;      // 52 full chunks
constexpr int TAIL = T_N - NFC*CL;  // 4 steps in tail chunk
constexpr int NCH  = NFC + 1;       // 53 chunks incl. tail
constexpr int FL   = 12;            // noise prefetch sub-chunk
constexpr int NFL  = CL / FL;       // 4
constexpr int ROWF = (T_N + 1) * 3; // floats per output path row

// d_ws layout (floats): trans [NCH][B][12] — slots 0..51 hold (M 9, v 3);
// scan overwrites slot c's first float4 with boundary state x_{48c}, c=0..52.
// 53*4096*12*4 B = 10.42 MB.

__global__ __launch_bounds__(64)
void sde_chunk_transforms(const float* __restrict__ A,
                          const float* __restrict__ bv,
                          const float* __restrict__ C,
                          const float* __restrict__ dv,
                          const float* __restrict__ noise,
                          float* __restrict__ trans)
{
    const int b = blockIdx.x * 64 + threadIdx.x;
    const int c = blockIdx.y;          // 0..51

    const float dt  = 0.002f;
    const float sdt = sqrtf(dt);

    float IA[3][3], Cs[3][3], bdt[3], ds[3];
#pragma unroll
    for (int i = 0; i < 3; ++i) {
        bdt[i] = bv[i] * dt;
        ds[i]  = dv[i] * sdt;
#pragma unroll
        for (int j = 0; j < 3; ++j) {
            IA[i][j] = A[i * 3 + j] * dt + (i == j ? 1.0f : 0.0f);
            Cs[i][j] = C[i * 3 + j] * sdt;
        }
    }

    float M[3][3] = {{1,0,0},{0,1,0},{0,0,1}};
    float v[3] = {0, 0, 0};

    const float* __restrict__ nb = noise + (size_t)c * CL * (B_N * 3) + (size_t)b * 3;
    const size_t nstride = (size_t)B_N * 3;

    float bufA[FL][3], bufB[FL][3];

    auto loadChunk = [&](float (&buf)[FL][3], int s) {
#pragma unroll
        for (int k = 0; k < FL; ++k) {
            const float* p = nb + ((size_t)s * FL + k) * nstride;
            buf[k][0] = p[0];
            buf[k][1] = p[1];
            buf[k][2] = p[2];
        }
    };

    auto compChunk = [&](const float (&buf)[FL][3]) {
#pragma unroll
        for (int k = 0; k < FL; ++k) {
            const float e[3] = { buf[k][0], buf[k][1], buf[k][2] };
            float S[3][3], t[3];
#pragma unroll
            for (int i = 0; i < 3; ++i) {
                t[i] = fmaf(e[i], ds[i], bdt[i]);
#pragma unroll
                for (int j = 0; j < 3; ++j)
                    S[i][j] = fmaf(e[i], Cs[i][j], IA[i][j]);
            }
            float nM[3][3], nv[3];
#pragma unroll
            for (int i = 0; i < 3; ++i) {
#pragma unroll
                for (int j = 0; j < 3; ++j)
                    nM[i][j] = fmaf(S[i][2], M[2][j], fmaf(S[i][1], M[1][j], S[i][0] * M[0][j]));
                nv[i] = fmaf(S[i][2], v[2], fmaf(S[i][1], v[1], S[i][0] * v[0])) + t[i];
            }
#pragma unroll
            for (int i = 0; i < 3; ++i) {
                v[i] = nv[i];
#pragma unroll
                for (int j = 0; j < 3; ++j) M[i][j] = nM[i][j];
            }
        }
    };

    // NFL = 4 (even): double-buffered pipeline
    loadChunk(bufA, 0);
    for (int s = 0; s < NFL; s += 2) {
        if (s + 1 < NFL) loadChunk(bufB, s + 1);
        compChunk(bufA);
        if (s + 2 < NFL) loadChunk(bufA, s + 2);
        if (s + 1 < NFL) compChunk(bufB);
    }

    float* tp = trans + ((size_t)c * B_N + b) * 12;
    float4 w0 = { M[0][0], M[0][1], M[0][2], M[1][0] };
    float4 w1 = { M[1][1], M[1][2], M[2][0], M[2][1] };
    float4 w2 = { M[2][2], v[0],    v[1],    v[2]    };
    ((float4*)tp)[0] = w0;
    ((float4*)tp)[1] = w1;
    ((float4*)tp)[2] = w2;
}

__global__ __launch_bounds__(64)
void sde_scan(const float* __restrict__ x0,
              float* __restrict__ trans)
{
    const int b = blockIdx.x * 64 + threadIdx.x;

    float x[3] = { x0[b * 3 + 0], x0[b * 3 + 1], x0[b * 3 + 2] };

    float4* tp0 = (float4*)(trans + (size_t)b * 12);
    const size_t cstride4 = (size_t)B_N * 3;   // float4 stride between chunk slots

    float4 a0 = tp0[0], a1 = tp0[1], a2 = tp0[2];

    for (int c = 0; c < NFC; ++c) {
        float4 b0, b1, b2;
        if (c + 1 < NFC) {
            const float4* tn = tp0 + (size_t)(c + 1) * cstride4;
            b0 = tn[0]; b1 = tn[1]; b2 = tn[2];
        }

        // overwrite slot c (already consumed) with boundary state x_{48c}
        tp0[(size_t)c * cstride4] = make_float4(x[0], x[1], x[2], 0.0f);

        const float n0 = fmaf(a0.x, x[0], fmaf(a0.y, x[1], fmaf(a0.z, x[2], a2.y)));
        const float n1 = fmaf(a0.w, x[0], fmaf(a1.x, x[1], fmaf(a1.y, x[2], a2.z)));
        const float n2 = fmaf(a1.z, x[0], fmaf(a1.w, x[1], fmaf(a2.x, x[2], a2.w)));
        x[0] = n0; x[1] = n1; x[2] = n2;

        a0 = b0; a1 = b1; a2 = b2;
    }

    // boundary for the tail chunk: x_{2496}
    tp0[(size_t)NFC * cstride4] = make_float4(x[0], x[1], x[2], 0.0f);
}

__global__ __launch_bounds__(256)
void sde_replay(const float* __restrict__ A,
                const float* __restrict__ bv,
                const float* __restrict__ C,
                const float* __restrict__ dv,
                const float* __restrict__ noise,
                const float* __restrict__ trans,
                float* __restrict__ out)
{
    const int widx = threadIdx.x >> 6;
    const int lane = threadIdx.x & 63;
    const int wg   = blockIdx.x * 4 + widx;   // 0..3391
    const int pg   = wg & 63;                 // path group
    const int c    = wg >> 6;                 // chunk 0..52
    const int b    = (pg << 6) | lane;

    const float dt  = 0.002f;
    const float sdt = sqrtf(dt);

    float Adt[3][3], Cs[3][3], bdt[3], dsv[3];
#pragma unroll
    for (int i = 0; i < 3; ++i) {
        bdt[i] = bv[i] * dt;
        dsv[i] = dv[i] * sdt;
#pragma unroll
        for (int j = 0; j < 3; ++j) {
            Adt[i][j] = A[i * 3 + j] * dt;
            Cs[i][j]  = C[i * 3 + j] * sdt;
        }
    }

    const float4 xb = *(const float4*)(trans + ((size_t)c * B_N + b) * 12);
    float x0r = xb.x, x1r = xb.y, x2r = xb.z;

    // write region starts at t = c*CL (64B-aligned: c*48*12 = 576c bytes)
    float* __restrict__ op = out + (size_t)b * ROWF + (size_t)c * CL * 3;

    // boundary state
    op[0] = x0r; op[1] = x1r; op[2] = x2r;
    op += 3;

    const float* __restrict__ nb = noise + (size_t)c * CL * (B_N * 3) + (size_t)b * 3;
    const size_t nstride = (size_t)B_N * 3;

    auto step = [&](float e0, float e1, float e2) {
        const float a0 = fmaf(Adt[0][2], x2r, fmaf(Adt[0][1], x1r, fmaf(Adt[0][0], x0r, bdt[0])));
        const float a1 = fmaf(Adt[1][2], x2r, fmaf(Adt[1][1], x1r, fmaf(Adt[1][0], x0r, bdt[1])));
        const float a2 = fmaf(Adt[2][2], x2r, fmaf(Adt[2][1], x1r, fmaf(Adt[2][0], x0r, bdt[2])));

        const float c0 = fmaf(Cs[0][2], x2r, fmaf(Cs[0][1], x1r, fmaf(Cs[0][0], x0r, dsv[0])));
        const float c1 = fmaf(Cs[1][2], x2r, fmaf(Cs[1][1], x1r, fmaf(Cs[1][0], x0r, dsv[1])));
        const float c2 = fmaf(Cs[2][2], x2r, fmaf(Cs[2][1], x1r, fmaf(Cs[2][0], x0r, dsv[2])));

        x0r = fmaf(c0, e0, x0r + a0);
        x1r = fmaf(c1, e1, x1r + a1);
        x2r = fmaf(c2, e2, x2r + a2);

        op[0] = x0r; op[1] = x1r; op[2] = x2r;
        op += 3;
    };

    if (c == NFC) {
        // tail: boundary x_2496 written above at t=2496; compute 4 steps,
        // writing t=2497..2500 (final partial line per path, 12 B)
#pragma unroll
        for (int k = 0; k < TAIL; ++k) {
            const float* p = nb + (size_t)k * nstride;
            step(p[0], p[1], p[2]);
        }
        return;
    }

    float bufA[FL][3], bufB[FL][3];

    auto loadChunk = [&](float (&buf)[FL][3], int s) {
#pragma unroll
        for (int k = 0; k < FL; ++k) {
            const float* p = nb + ((size_t)s * FL + k) * nstride;
            buf[k][0] = p[0];
            buf[k][1] = p[1];
            buf[k][2] = p[2];
        }
    };

    auto doFlush = [&](const float (&buf)[FL][3], auto nconst) {
        constexpr int N = decltype(nconst)::value;
#pragma unroll
        for (int k = 0; k < N; ++k)
            step(buf[k][0], buf[k][1], buf[k][2]);
    };

    // 47 computed states: flushes of 12,12,12,11 (noise steps 0..46)
    loadChunk(bufA, 0);
    loadChunk(bufB, 1);
    doFlush(bufA, std::integral_constant<int, FL>{});
    loadChunk(bufA, 2);
    doFlush(bufB, std::integral_constant<int, FL>{});
    loadChunk(bufB, 3);
    doFlush(bufA, std::integral_constant<int, FL>{});
    doFlush(bufB, std::integral_constant<int, FL - 1>{});
}

extern "C" void kernel_launch(void* const* d_in, const int* in_sizes, int n_in,
                              void* d_out, int out_size, void* d_ws, size_t ws_size,
                              hipStream_t stream) {
    const float* x0    = (const float*)d_in[0];
    const float* A     = (const float*)d_in[1];
    const float* bv    = (const float*)d_in[2];
    const float* C     = (const float*)d_in[3];
    const float* dv    = (const float*)d_in[4];
    const float* noise = (const float*)d_in[5];
    float* out = (float*)d_out;

    float* trans = (float*)d_ws;   // 10.42 MB

    dim3 gridPC(B_N / 64, NFC);

    sde_chunk_transforms<<<gridPC, 64, 0, stream>>>(A, bv, C, dv, noise, trans);
    sde_scan<<<B_N / 64, 64, 0, stream>>>(x0, trans);
    sde_replay<<<(B_N / 64) * NCH / 4, 256, 0, stream>>>(A, bv, C, dv, noise, trans, out);
}

// Round 8
// 91.901 us; speedup vs baseline: 1.2438x; 1.2438x over previous
//
#include <hip/hip_runtime.h>
#include <math.h>
#include <type_traits>

// SDE Euler-Maruyama path generator — affine-scan decomposition, v8.
//   step:  x' = S_k x + t_k,  S_k = I + dt*A + diag(dW_k)*C,  t_k = dt*b + dW_k*d
// CL=48-step chunks -> per-(path,chunk) output region = 48 states = 576 B =
// 9 whole 64B lines, aligned (boundary state written first). Replay flushes
// 12 states at a time through a wave-private LDS transpose; each store
// instruction writes one path's full 144 B contiguously (16-lane groups),
// so L2 lines complete immediately -> no partial-line evictions, no seams.

constexpr int B_N  = 4096;
constexpr int T_N  = 2500;
constexpr int CL   = 48;            // steps per chunk (576 B regions, line-aligned)
constexpr int NFC  = T_N / CL;      // 52 full chunks
constexpr int TAIL = T_N - NFC*CL;  // 4 steps in tail chunk
constexpr int NCH  = NFC + 1;       // 53 chunks incl. tail
constexpr int FL   = 12;            // noise prefetch / flush sub-chunk (states)
constexpr int ROWF = (T_N + 1) * 3; // floats per output path row

template <int N> using ic = std::integral_constant<int, N>;

// d_ws layout (floats): trans [NCH][B][12] — slots 0..51 hold (M 9, v 3);
// scan overwrites slot c's first float4 with boundary state x_{48c}, c=0..52.

__global__ __launch_bounds__(64)
void sde_chunk_transforms(const float* __restrict__ A,
                          const float* __restrict__ bv,
                          const float* __restrict__ C,
                          const float* __restrict__ dv,
                          const float* __restrict__ noise,
                          float* __restrict__ trans)
{
    const int b = blockIdx.x * 64 + threadIdx.x;
    const int c = blockIdx.y;          // 0..51

    const float dt  = 0.002f;
    const float sdt = sqrtf(dt);

    float IA[3][3], Cs[3][3], bdt[3], ds[3];
#pragma unroll
    for (int i = 0; i < 3; ++i) {
        bdt[i] = bv[i] * dt;
        ds[i]  = dv[i] * sdt;
#pragma unroll
        for (int j = 0; j < 3; ++j) {
            IA[i][j] = A[i * 3 + j] * dt + (i == j ? 1.0f : 0.0f);
            Cs[i][j] = C[i * 3 + j] * sdt;
        }
    }

    float M[3][3] = {{1,0,0},{0,1,0},{0,0,1}};
    float v[3] = {0, 0, 0};

    const float* __restrict__ nb = noise + (size_t)c * CL * (B_N * 3) + (size_t)b * 3;
    const size_t nstride = (size_t)B_N * 3;

    float bufA[FL][3], bufB[FL][3];

    auto loadChunk = [&](float (&buf)[FL][3], int s) {
#pragma unroll
        for (int k = 0; k < FL; ++k) {
            const float* p = nb + ((size_t)s * FL + k) * nstride;
            buf[k][0] = p[0];
            buf[k][1] = p[1];
            buf[k][2] = p[2];
        }
    };

    auto compChunk = [&](const float (&buf)[FL][3]) {
#pragma unroll
        for (int k = 0; k < FL; ++k) {
            const float e[3] = { buf[k][0], buf[k][1], buf[k][2] };
            float S[3][3], t[3];
#pragma unroll
            for (int i = 0; i < 3; ++i) {
                t[i] = fmaf(e[i], ds[i], bdt[i]);
#pragma unroll
                for (int j = 0; j < 3; ++j)
                    S[i][j] = fmaf(e[i], Cs[i][j], IA[i][j]);
            }
            float nM[3][3], nv[3];
#pragma unroll
            for (int i = 0; i < 3; ++i) {
#pragma unroll
                for (int j = 0; j < 3; ++j)
                    nM[i][j] = fmaf(S[i][2], M[2][j], fmaf(S[i][1], M[1][j], S[i][0] * M[0][j]));
                nv[i] = fmaf(S[i][2], v[2], fmaf(S[i][1], v[1], S[i][0] * v[0])) + t[i];
            }
#pragma unroll
            for (int i = 0; i < 3; ++i) {
                v[i] = nv[i];
#pragma unroll
                for (int j = 0; j < 3; ++j) M[i][j] = nM[i][j];
            }
        }
    };

    // CL/FL = 4 sub-chunks, double-buffered
    loadChunk(bufA, 0);
    loadChunk(bufB, 1);
    compChunk(bufA);
    loadChunk(bufA, 2);
    compChunk(bufB);
    loadChunk(bufB, 3);
    compChunk(bufA);
    compChunk(bufB);

    float* tp = trans + ((size_t)c * B_N + b) * 12;
    float4 w0 = { M[0][0], M[0][1], M[0][2], M[1][0] };
    float4 w1 = { M[1][1], M[1][2], M[2][0], M[2][1] };
    float4 w2 = { M[2][2], v[0],    v[1],    v[2]    };
    ((float4*)tp)[0] = w0;
    ((float4*)tp)[1] = w1;
    ((float4*)tp)[2] = w2;
}

__global__ __launch_bounds__(64)
void sde_scan(const float* __restrict__ x0,
              float* __restrict__ trans)
{
    const int b = blockIdx.x * 64 + threadIdx.x;

    float x[3] = { x0[b * 3 + 0], x0[b * 3 + 1], x0[b * 3 + 2] };

    float4* tp0 = (float4*)(trans + (size_t)b * 12);
    const size_t cstride4 = (size_t)B_N * 3;   // float4 stride between chunk slots

    float4 a0 = tp0[0], a1 = tp0[1], a2 = tp0[2];

    for (int c = 0; c < NFC; ++c) {
        float4 b0, b1, b2;
        if (c + 1 < NFC) {
            const float4* tn = tp0 + (size_t)(c + 1) * cstride4;
            b0 = tn[0]; b1 = tn[1]; b2 = tn[2];
        }

        // overwrite slot c (already consumed) with boundary state x_{48c}
        tp0[(size_t)c * cstride4] = make_float4(x[0], x[1], x[2], 0.0f);

        const float n0 = fmaf(a0.x, x[0], fmaf(a0.y, x[1], fmaf(a0.z, x[2], a2.y)));
        const float n1 = fmaf(a0.w, x[0], fmaf(a1.x, x[1], fmaf(a1.y, x[2], a2.z)));
        const float n2 = fmaf(a1.z, x[0], fmaf(a1.w, x[1], fmaf(a2.x, x[2], a2.w)));
        x[0] = n0; x[1] = n1; x[2] = n2;

        a0 = b0; a1 = b1; a2 = b2;
    }

    // boundary for the tail chunk: x_{2496}
    tp0[(size_t)NFC * cstride4] = make_float4(x[0], x[1], x[2], 0.0f);
}

__global__ __launch_bounds__(256, 3)
void sde_replay(const float* __restrict__ A,
                const float* __restrict__ bv,
                const float* __restrict__ C,
                const float* __restrict__ dv,
                const float* __restrict__ noise,
                const float* __restrict__ trans,
                float* __restrict__ out)
{
    __shared__ float lds[4][64][37];   // per-wave flush tile: 12 states = 36 floats (+1 pad)

    const int widx = threadIdx.x >> 6;
    const int lane = threadIdx.x & 63;
    const int wg   = blockIdx.x * 4 + widx;   // 0..3391
    const int pg   = wg & 63;                 // path group
    const int c    = wg >> 6;                 // chunk 0..52
    const int b    = (pg << 6) | lane;

    const float dt  = 0.002f;
    const float sdt = sqrtf(dt);

    float Adt[3][3], Cs[3][3], bdt[3], dsv[3];
#pragma unroll
    for (int i = 0; i < 3; ++i) {
        bdt[i] = bv[i] * dt;
        dsv[i] = dv[i] * sdt;
#pragma unroll
        for (int j = 0; j < 3; ++j) {
            Adt[i][j] = A[i * 3 + j] * dt;
            Cs[i][j]  = C[i * 3 + j] * sdt;
        }
    }

    const float4 xb = *(const float4*)(trans + ((size_t)c * B_N + b) * 12);
    float x0r = xb.x, x1r = xb.y, x2r = xb.z;

    const float* __restrict__ nb = noise + (size_t)c * CL * (B_N * 3) + (size_t)b * 3;
    const size_t nstride = (size_t)B_N * 3;

    auto stepf = [&](float e0, float e1, float e2) {
        const float a0 = fmaf(Adt[0][2], x2r, fmaf(Adt[0][1], x1r, fmaf(Adt[0][0], x0r, bdt[0])));
        const float a1 = fmaf(Adt[1][2], x2r, fmaf(Adt[1][1], x1r, fmaf(Adt[1][0], x0r, bdt[1])));
        const float a2 = fmaf(Adt[2][2], x2r, fmaf(Adt[2][1], x1r, fmaf(Adt[2][0], x0r, bdt[2])));

        const float c0 = fmaf(Cs[0][2], x2r, fmaf(Cs[0][1], x1r, fmaf(Cs[0][0], x0r, dsv[0])));
        const float c1 = fmaf(Cs[1][2], x2r, fmaf(Cs[1][1], x1r, fmaf(Cs[1][0], x0r, dsv[1])));
        const float c2 = fmaf(Cs[2][2], x2r, fmaf(Cs[2][1], x1r, fmaf(Cs[2][0], x0r, dsv[2])));

        x0r = fmaf(c0, e0, x0r + a0);
        x1r = fmaf(c1, e1, x1r + a1);
        x2r = fmaf(c2, e2, x2r + a2);
    };

    if (c == NFC) {
        // tail: 5 states (boundary x_2496 + 4 computed), 60 B at aligned offset
        float* op = out + (size_t)b * ROWF + (size_t)NFC * CL * 3;
        op[0] = x0r; op[1] = x1r; op[2] = x2r; op += 3;
#pragma unroll
        for (int k = 0; k < TAIL; ++k) {
            const float* p = nb + (size_t)k * nstride;
            stepf(p[0], p[1], p[2]);
            op[0] = x0r; op[1] = x1r; op[2] = x2r; op += 3;
        }
        return;
    }

    float (*tile)[37] = lds[widx];

    // store roles: instruction i writes paths {4i..4i+3}; 16-lane group h
    // covers one path's full 144 B flush contiguously (m = float-triple idx).
    const int  h   = lane >> 4;     // 0..3
    const int  m   = lane & 15;     // 0..15
    const bool act = m < 12;
    float* const outbase = out + (size_t)(pg << 6) * ROWF + (size_t)c * (CL * 3);

    float bufA[FL][3], bufB[FL][3];

    auto loadN = [&](float (&buf)[FL][3], int base, auto cntc) {
        constexpr int CNT = decltype(cntc)::value;
#pragma unroll
        for (int k = 0; k < CNT; ++k) {
            const float* p = nb + (size_t)(base + k) * nstride;
            buf[k][0] = p[0];
            buf[k][1] = p[1];
            buf[k][2] = p[2];
        }
    };

    auto warGuard = [&]() {
        // previous storeFlush's ds_reads must be complete before tile reuse
        asm volatile("s_waitcnt lgkmcnt(0)" ::: "memory");
        __builtin_amdgcn_sched_barrier(0);
    };

    auto storeFlush = [&](int f) {
        // RAW: tile writes visible before cross-lane reads
        asm volatile("s_waitcnt lgkmcnt(0)" ::: "memory");
        __builtin_amdgcn_sched_barrier(0);
        if (act) {
#pragma unroll
            for (int i = 0; i < 16; ++i) {
                const int p = i * 4 + h;
                const float v0 = tile[p][m * 3 + 0];
                const float v1 = tile[p][m * 3 + 1];
                const float v2 = tile[p][m * 3 + 2];
                float* dst = outbase + (size_t)p * ROWF + f * (FL * 3) + m * 3;
                dst[0] = v0; dst[1] = v1; dst[2] = v2;
            }
        }
    };

    // noise groups: G0=eps[0..10], G1=eps[11..22], G2=eps[23..34], G3=eps[35..46]
    loadN(bufA, 0,  ic<11>{});
    loadN(bufB, 11, ic<12>{});

    // FLUSH 0: states 0..11 (boundary + step(eps0..10))
    tile[lane][0] = x0r; tile[lane][1] = x1r; tile[lane][2] = x2r;
#pragma unroll
    for (int k = 0; k < 11; ++k) {
        stepf(bufA[k][0], bufA[k][1], bufA[k][2]);
        tile[lane][(k + 1) * 3 + 0] = x0r;
        tile[lane][(k + 1) * 3 + 1] = x1r;
        tile[lane][(k + 1) * 3 + 2] = x2r;
    }
    loadN(bufA, 23, ic<12>{});
    storeFlush(0);

    // FLUSH 1: states 12..23 = step(eps11..22) = bufB
    warGuard();
#pragma unroll
    for (int k = 0; k < 12; ++k) {
        stepf(bufB[k][0], bufB[k][1], bufB[k][2]);
        tile[lane][k * 3 + 0] = x0r;
        tile[lane][k * 3 + 1] = x1r;
        tile[lane][k * 3 + 2] = x2r;
    }
    loadN(bufB, 35, ic<12>{});
    storeFlush(1);

    // FLUSH 2: states 24..35 = step(eps23..34) = bufA
    warGuard();
#pragma unroll
    for (int k = 0; k < 12; ++k) {
        stepf(bufA[k][0], bufA[k][1], bufA[k][2]);
        tile[lane][k * 3 + 0] = x0r;
        tile[lane][k * 3 + 1] = x1r;
        tile[lane][k * 3 + 2] = x2r;
    }
    storeFlush(2);

    // FLUSH 3: states 36..47 = step(eps35..46) = bufB
    warGuard();
#pragma unroll
    for (int k = 0; k < 12; ++k) {
        stepf(bufB[k][0], bufB[k][1], bufB[k][2]);
        tile[lane][k * 3 + 0] = x0r;
        tile[lane][k * 3 + 1] = x1r;
        tile[lane][k * 3 + 2] = x2r;
    }
    storeFlush(3);
}

extern "C" void kernel_launch(void* const* d_in, const int* in_sizes, int n_in,
                              void* d_out, int out_size, void* d_ws, size_t ws_size,
                              hipStream_t stream) {
    const float* x0    = (const float*)d_in[0];
    const float* A     = (const float*)d_in[1];
    const float* bv    = (const float*)d_in[2];
    const float* C     = (const float*)d_in[3];
    const float* dv    = (const float*)d_in[4];
    const float* noise = (const float*)d_in[5];
    float* out = (float*)d_out;

    float* trans = (float*)d_ws;   // 10.42 MB

    dim3 gridPC(B_N / 64, NFC);

    sde_chunk_transforms<<<gridPC, 64, 0, stream>>>(A, bv, C, dv, noise, trans);
    sde_scan<<<B_N / 64, 64, 0, stream>>>(x0, trans);
    sde_replay<<<(B_N / 64) * NCH / 4, 256, 0, stream>>>(A, bv, C, dv, noise, trans, out);
}

// Round 9
// 90.907 us; speedup vs baseline: 1.2574x; 1.0109x over previous
//
#include <hip/hip_runtime.h>
#include <math.h>
#include <type_traits>

// SDE Euler-Maruyama path generator — affine-scan decomposition, v9.
//   step:  x' = S_k x + t_k,  S_k = I + dt*A + diag(dW_k)*C,  t_k = dt*b + dW_k*d
// CL=48-step chunks -> per-(path,chunk) region = 576 B = 9 whole 64B lines,
// aligned (boundary state first). Replay flushes 16 states (192 B = 3 whole
// lines, line-aligned -> zero straddling) through a TRANSPOSED conflict-free
// LDS tile [48][66]: writes (2(3k+c)+lane)%32 and reads (6m+2c+4i+h)%32 both
// hit every bank exactly twice (free). Stores: 16-lane group = one path's
// 192 B contiguous, all 64 lanes active, dwordx3.

constexpr int B_N  = 4096;
constexpr int T_N  = 2500;
constexpr int CL   = 48;            // steps per chunk
constexpr int NFC  = T_N / CL;      // 52 full chunks
constexpr int TAIL = T_N - NFC*CL;  // 4 steps in tail chunk
constexpr int NCH  = NFC + 1;       // 53 chunks incl. tail
constexpr int FLP  = 12;            // phase-1 noise prefetch sub-chunk
constexpr int FL   = 16;            // replay flush size (states) = 192 B aligned
constexpr int ROWF = (T_N + 1) * 3; // floats per output path row

template <int N> using ic = std::integral_constant<int, N>;

// d_ws layout (floats): trans [NCH][B][12] — slots 0..51 hold (M 9, v 3);
// scan overwrites slot c's first float4 with boundary state x_{48c}, c=0..52.

__global__ __launch_bounds__(64)
void sde_chunk_transforms(const float* __restrict__ A,
                          const float* __restrict__ bv,
                          const float* __restrict__ C,
                          const float* __restrict__ dv,
                          const float* __restrict__ noise,
                          float* __restrict__ trans)
{
    const int b = blockIdx.x * 64 + threadIdx.x;
    const int c = blockIdx.y;          // 0..51

    const float dt  = 0.002f;
    const float sdt = sqrtf(dt);

    float IA[3][3], Cs[3][3], bdt[3], ds[3];
#pragma unroll
    for (int i = 0; i < 3; ++i) {
        bdt[i] = bv[i] * dt;
        ds[i]  = dv[i] * sdt;
#pragma unroll
        for (int j = 0; j < 3; ++j) {
            IA[i][j] = A[i * 3 + j] * dt + (i == j ? 1.0f : 0.0f);
            Cs[i][j] = C[i * 3 + j] * sdt;
        }
    }

    float M[3][3] = {{1,0,0},{0,1,0},{0,0,1}};
    float v[3] = {0, 0, 0};

    const float* __restrict__ nb = noise + (size_t)c * CL * (B_N * 3) + (size_t)b * 3;
    const size_t nstride = (size_t)B_N * 3;

    float bufA[FLP][3], bufB[FLP][3];

    auto loadChunk = [&](float (&buf)[FLP][3], int s) {
#pragma unroll
        for (int k = 0; k < FLP; ++k) {
            const float* p = nb + ((size_t)s * FLP + k) * nstride;
            buf[k][0] = p[0];
            buf[k][1] = p[1];
            buf[k][2] = p[2];
        }
    };

    auto compChunk = [&](const float (&buf)[FLP][3]) {
#pragma unroll
        for (int k = 0; k < FLP; ++k) {
            const float e[3] = { buf[k][0], buf[k][1], buf[k][2] };
            float S[3][3], t[3];
#pragma unroll
            for (int i = 0; i < 3; ++i) {
                t[i] = fmaf(e[i], ds[i], bdt[i]);
#pragma unroll
                for (int j = 0; j < 3; ++j)
                    S[i][j] = fmaf(e[i], Cs[i][j], IA[i][j]);
            }
            float nM[3][3], nv[3];
#pragma unroll
            for (int i = 0; i < 3; ++i) {
#pragma unroll
                for (int j = 0; j < 3; ++j)
                    nM[i][j] = fmaf(S[i][2], M[2][j], fmaf(S[i][1], M[1][j], S[i][0] * M[0][j]));
                nv[i] = fmaf(S[i][2], v[2], fmaf(S[i][1], v[1], S[i][0] * v[0])) + t[i];
            }
#pragma unroll
            for (int i = 0; i < 3; ++i) {
                v[i] = nv[i];
#pragma unroll
                for (int j = 0; j < 3; ++j) M[i][j] = nM[i][j];
            }
        }
    };

    // CL/FLP = 4 sub-chunks, double-buffered
    loadChunk(bufA, 0);
    loadChunk(bufB, 1);
    compChunk(bufA);
    loadChunk(bufA, 2);
    compChunk(bufB);
    loadChunk(bufB, 3);
    compChunk(bufA);
    compChunk(bufB);

    float* tp = trans + ((size_t)c * B_N + b) * 12;
    float4 w0 = { M[0][0], M[0][1], M[0][2], M[1][0] };
    float4 w1 = { M[1][1], M[1][2], M[2][0], M[2][1] };
    float4 w2 = { M[2][2], v[0],    v[1],    v[2]    };
    ((float4*)tp)[0] = w0;
    ((float4*)tp)[1] = w1;
    ((float4*)tp)[2] = w2;
}

__global__ __launch_bounds__(64)
void sde_scan(const float* __restrict__ x0,
              float* __restrict__ trans)
{
    const int b = blockIdx.x * 64 + threadIdx.x;

    float x[3] = { x0[b * 3 + 0], x0[b * 3 + 1], x0[b * 3 + 2] };

    float4* tp0 = (float4*)(trans + (size_t)b * 12);
    const size_t cstride4 = (size_t)B_N * 3;   // float4 stride between chunk slots

    float4 a0 = tp0[0], a1 = tp0[1], a2 = tp0[2];

    for (int c = 0; c < NFC; ++c) {
        float4 b0, b1, b2;
        if (c + 1 < NFC) {
            const float4* tn = tp0 + (size_t)(c + 1) * cstride4;
            b0 = tn[0]; b1 = tn[1]; b2 = tn[2];
        }

        // overwrite slot c (already consumed) with boundary state x_{48c}
        tp0[(size_t)c * cstride4] = make_float4(x[0], x[1], x[2], 0.0f);

        const float n0 = fmaf(a0.x, x[0], fmaf(a0.y, x[1], fmaf(a0.z, x[2], a2.y)));
        const float n1 = fmaf(a0.w, x[0], fmaf(a1.x, x[1], fmaf(a1.y, x[2], a2.z)));
        const float n2 = fmaf(a1.z, x[0], fmaf(a1.w, x[1], fmaf(a2.x, x[2], a2.w)));
        x[0] = n0; x[1] = n1; x[2] = n2;

        a0 = b0; a1 = b1; a2 = b2;
    }

    // boundary for the tail chunk: x_{2496}
    tp0[(size_t)NFC * cstride4] = make_float4(x[0], x[1], x[2], 0.0f);
}

__global__ __launch_bounds__(256)
void sde_replay(const float* __restrict__ A,
                const float* __restrict__ bv,
                const float* __restrict__ C,
                const float* __restrict__ dv,
                const float* __restrict__ noise,
                const float* __restrict__ trans,
                float* __restrict__ out)
{
    __shared__ float lds[4][FL * 3][66];   // transposed tile: [state*3+c][path], conflict-free

    const int widx = threadIdx.x >> 6;
    const int lane = threadIdx.x & 63;
    const int wg   = blockIdx.x * 4 + widx;   // 0..3391
    const int pg   = wg & 63;                 // path group
    const int c    = wg >> 6;                 // chunk 0..52
    const int b    = (pg << 6) | lane;

    const float dt  = 0.002f;
    const float sdt = sqrtf(dt);

    float Adt[3][3], Cs[3][3], bdt[3], dsv[3];
#pragma unroll
    for (int i = 0; i < 3; ++i) {
        bdt[i] = bv[i] * dt;
        dsv[i] = dv[i] * sdt;
#pragma unroll
        for (int j = 0; j < 3; ++j) {
            Adt[i][j] = A[i * 3 + j] * dt;
            Cs[i][j]  = C[i * 3 + j] * sdt;
        }
    }

    const float4 xb = *(const float4*)(trans + ((size_t)c * B_N + b) * 12);
    float x0r = xb.x, x1r = xb.y, x2r = xb.z;

    const float* __restrict__ nb = noise + (size_t)c * CL * (B_N * 3) + (size_t)b * 3;
    const size_t nstride = (size_t)B_N * 3;

    auto stepf = [&](float e0, float e1, float e2) {
        const float a0 = fmaf(Adt[0][2], x2r, fmaf(Adt[0][1], x1r, fmaf(Adt[0][0], x0r, bdt[0])));
        const float a1 = fmaf(Adt[1][2], x2r, fmaf(Adt[1][1], x1r, fmaf(Adt[1][0], x0r, bdt[1])));
        const float a2 = fmaf(Adt[2][2], x2r, fmaf(Adt[2][1], x1r, fmaf(Adt[2][0], x0r, bdt[2])));

        const float c0 = fmaf(Cs[0][2], x2r, fmaf(Cs[0][1], x1r, fmaf(Cs[0][0], x0r, dsv[0])));
        const float c1 = fmaf(Cs[1][2], x2r, fmaf(Cs[1][1], x1r, fmaf(Cs[1][0], x0r, dsv[1])));
        const float c2 = fmaf(Cs[2][2], x2r, fmaf(Cs[2][1], x1r, fmaf(Cs[2][0], x0r, dsv[2])));

        x0r = fmaf(c0, e0, x0r + a0);
        x1r = fmaf(c1, e1, x1r + a1);
        x2r = fmaf(c2, e2, x2r + a2);
    };

    if (c == NFC) {
        // tail: 5 states (boundary x_2496 + 4 computed), 60 B at aligned offset
        float* op = out + (size_t)b * ROWF + (size_t)NFC * CL * 3;
        op[0] = x0r; op[1] = x1r; op[2] = x2r; op += 3;
#pragma unroll
        for (int k = 0; k < TAIL; ++k) {
            const float* p = nb + (size_t)k * nstride;
            stepf(p[0], p[1], p[2]);
            op[0] = x0r; op[1] = x1r; op[2] = x2r; op += 3;
        }
        return;
    }

    float (*tile)[66] = lds[widx];

    // store roles: 16-lane group h covers path p=4i+h's full 192 B flush
    // contiguously; m = triple index 0..15. All 64 lanes active.
    const int h = lane >> 4;     // 0..3
    const int m = lane & 15;     // 0..15
    float* const outbase = out + (size_t)(pg << 6) * ROWF + (size_t)c * (CL * 3);

    // put state into tile row-transposed: rows = state*3+comp, col = lane(path)
    auto writeState = [&](int k) {
        tile[3 * k + 0][lane] = x0r;
        tile[3 * k + 1][lane] = x1r;
        tile[3 * k + 2][lane] = x2r;
    };

    auto warGuard = [&]() {
        // previous storeFlush's ds_reads must complete before tile reuse
        asm volatile("s_waitcnt lgkmcnt(0)" ::: "memory");
        __builtin_amdgcn_sched_barrier(0);
    };

    auto storeFlush = [&](int f) {
        // RAW: tile writes visible before cross-lane reads
        asm volatile("s_waitcnt lgkmcnt(0)" ::: "memory");
        __builtin_amdgcn_sched_barrier(0);
#pragma unroll
        for (int i = 0; i < 16; ++i) {
            const int p = i * 4 + h;
            const float v0 = tile[3 * m + 0][p];
            const float v1 = tile[3 * m + 1][p];
            const float v2 = tile[3 * m + 2][p];
            float* dst = outbase + (size_t)p * ROWF + f * (FL * 3) + m * 3;
            dst[0] = v0; dst[1] = v1; dst[2] = v2;
        }
    };

    float bufA[FL][3], bufB[FL][3];

    auto loadN = [&](float (&buf)[FL][3], int base, auto cntc) {
        constexpr int CNT = decltype(cntc)::value;
#pragma unroll
        for (int k = 0; k < CNT; ++k) {
            const float* p = nb + (size_t)(base + k) * nstride;
            buf[k][0] = p[0];
            buf[k][1] = p[1];
            buf[k][2] = p[2];
        }
    };

    // noise groups: G0=eps[0..14], G1=eps[15..30], G2=eps[31..46]
    loadN(bufA, 0,  ic<15>{});
    loadN(bufB, 15, ic<16>{});

    // FLUSH 0: states 0..15 (boundary + step(eps0..14))
    writeState(0);
#pragma unroll
    for (int k = 0; k < 15; ++k) {
        stepf(bufA[k][0], bufA[k][1], bufA[k][2]);
        writeState(k + 1);
    }
    loadN(bufA, 31, ic<16>{});
    storeFlush(0);

    // FLUSH 1: states 16..31 = step(eps15..30) = bufB
    warGuard();
#pragma unroll
    for (int k = 0; k < 16; ++k) {
        stepf(bufB[k][0], bufB[k][1], bufB[k][2]);
        writeState(k);
    }
    storeFlush(1);

    // FLUSH 2: states 32..47 = step(eps31..46) = bufA
    warGuard();
#pragma unroll
    for (int k = 0; k < 16; ++k) {
        stepf(bufA[k][0], bufA[k][1], bufA[k][2]);
        writeState(k);
    }
    storeFlush(2);
}

extern "C" void kernel_launch(void* const* d_in, const int* in_sizes, int n_in,
                              void* d_out, int out_size, void* d_ws, size_t ws_size,
                              hipStream_t stream) {
    const float* x0    = (const float*)d_in[0];
    const float* A     = (const float*)d_in[1];
    const float* bv    = (const float*)d_in[2];
    const float* C     = (const float*)d_in[3];
    const float* dv    = (const float*)d_in[4];
    const float* noise = (const float*)d_in[5];
    float* out = (float*)d_out;

    float* trans = (float*)d_ws;   // 10.42 MB

    dim3 gridPC(B_N / 64, NFC);

    sde_chunk_transforms<<<gridPC, 64, 0, stream>>>(A, bv, C, dv, noise, trans);
    sde_scan<<<B_N / 64, 64, 0, stream>>>(x0, trans);
    sde_replay<<<(B_N / 64) * NCH / 4, 256, 0, stream>>>(A, bv, C, dv, noise, trans, out);
}

// Round 10
// 83.108 us; speedup vs baseline: 1.3754x; 1.0938x over previous
//
#include <hip/hip_runtime.h>
#include <math.h>
#include <type_traits>

// SDE Euler-Maruyama path generator — affine-scan decomposition, v10.
//   step:  x' = S_k x + t_k,  S_k = I + dt*A + diag(dW_k)*C,  t_k = dt*b + dW_k*d
// KEY: output row stride = 30012 B == 60 (mod 64), so chunk regions can only be
// line-aligned PER PATH: state t of path p is 64B-aligned iff t == 11p (mod 16).
// Each path gets phase phi_p = (11p)&15; wave c writes states
// [48c+phi_p, 48c+48+phi_p) -> every 192B store segment = 3 whole aligned lines
// for EVERY path. Rolling 32-state LDS tile absorbs the per-lane phase lag.
// Wave 0 writes head states [0,phi) scalar; wave 51 masks t<=2500; tail wave
// (c=52) writes [2496+phi, 2501) for phi<=4.

constexpr int B_N  = 4096;
constexpr int T_N  = 2500;
constexpr int CL   = 48;            // steps per chunk
constexpr int NFC  = T_N / CL;      // 52 full chunks
constexpr int NCH  = NFC + 1;       // 53 (incl. tail wave)
constexpr int FLP  = 12;            // phase-1 noise prefetch sub-chunk
constexpr int ROWF = (T_N + 1) * 3; // floats per output path row

template <int N> using ic = std::integral_constant<int, N>;

// d_ws (floats): trans [NCH][B][12] — slots 0..51 hold (M 9, v 3); scan
// overwrites slot c's first float4 with boundary state x_{48c}, c=0..52.

__global__ __launch_bounds__(64)
void sde_chunk_transforms(const float* __restrict__ A,
                          const float* __restrict__ bv,
                          const float* __restrict__ C,
                          const float* __restrict__ dv,
                          const float* __restrict__ noise,
                          float* __restrict__ trans)
{
    const int b = blockIdx.x * 64 + threadIdx.x;
    const int c = blockIdx.y;          // 0..51

    const float dt  = 0.002f;
    const float sdt = sqrtf(dt);

    float IA[3][3], Cs[3][3], bdt[3], ds[3];
#pragma unroll
    for (int i = 0; i < 3; ++i) {
        bdt[i] = bv[i] * dt;
        ds[i]  = dv[i] * sdt;
#pragma unroll
        for (int j = 0; j < 3; ++j) {
            IA[i][j] = A[i * 3 + j] * dt + (i == j ? 1.0f : 0.0f);
            Cs[i][j] = C[i * 3 + j] * sdt;
        }
    }

    float M[3][3] = {{1,0,0},{0,1,0},{0,0,1}};
    float v[3] = {0, 0, 0};

    const float* __restrict__ nb = noise + (size_t)c * CL * (B_N * 3) + (size_t)b * 3;
    const size_t nstride = (size_t)B_N * 3;

    float bufA[FLP][3], bufB[FLP][3];

    auto loadChunk = [&](float (&buf)[FLP][3], int s) {
#pragma unroll
        for (int k = 0; k < FLP; ++k) {
            const float* p = nb + ((size_t)s * FLP + k) * nstride;
            buf[k][0] = p[0];
            buf[k][1] = p[1];
            buf[k][2] = p[2];
        }
    };

    auto compChunk = [&](const float (&buf)[FLP][3]) {
#pragma unroll
        for (int k = 0; k < FLP; ++k) {
            const float e[3] = { buf[k][0], buf[k][1], buf[k][2] };
            float S[3][3], t[3];
#pragma unroll
            for (int i = 0; i < 3; ++i) {
                t[i] = fmaf(e[i], ds[i], bdt[i]);
#pragma unroll
                for (int j = 0; j < 3; ++j)
                    S[i][j] = fmaf(e[i], Cs[i][j], IA[i][j]);
            }
            float nM[3][3], nv[3];
#pragma unroll
            for (int i = 0; i < 3; ++i) {
#pragma unroll
                for (int j = 0; j < 3; ++j)
                    nM[i][j] = fmaf(S[i][2], M[2][j], fmaf(S[i][1], M[1][j], S[i][0] * M[0][j]));
                nv[i] = fmaf(S[i][2], v[2], fmaf(S[i][1], v[1], S[i][0] * v[0])) + t[i];
            }
#pragma unroll
            for (int i = 0; i < 3; ++i) {
                v[i] = nv[i];
#pragma unroll
                for (int j = 0; j < 3; ++j) M[i][j] = nM[i][j];
            }
        }
    };

    loadChunk(bufA, 0);
    loadChunk(bufB, 1);
    compChunk(bufA);
    loadChunk(bufA, 2);
    compChunk(bufB);
    loadChunk(bufB, 3);
    compChunk(bufA);
    compChunk(bufB);

    float* tp = trans + ((size_t)c * B_N + b) * 12;
    float4 w0 = { M[0][0], M[0][1], M[0][2], M[1][0] };
    float4 w1 = { M[1][1], M[1][2], M[2][0], M[2][1] };
    float4 w2 = { M[2][2], v[0],    v[1],    v[2]    };
    ((float4*)tp)[0] = w0;
    ((float4*)tp)[1] = w1;
    ((float4*)tp)[2] = w2;
}

__global__ __launch_bounds__(64)
void sde_scan(const float* __restrict__ x0,
              float* __restrict__ trans)
{
    const int b = blockIdx.x * 64 + threadIdx.x;

    float x[3] = { x0[b * 3 + 0], x0[b * 3 + 1], x0[b * 3 + 2] };

    float4* tp0 = (float4*)(trans + (size_t)b * 12);
    const size_t cs = (size_t)B_N * 3;   // float4 stride between chunk slots

    float4 qa0, qa1, qa2, qb0, qb1, qb2, qc0, qc1, qc2, qd0, qd1, qd2;

    auto L = [&](int s, float4& r0, float4& r1, float4& r2) {
        const float4* tn = tp0 + (size_t)s * cs;
        r0 = tn[0]; r1 = tn[1]; r2 = tn[2];
    };
    auto useSlot = [&](int s, const float4& a0, const float4& a1, const float4& a2) {
        // overwrite slot (already consumed) with boundary state x_{48s}
        tp0[(size_t)s * cs] = make_float4(x[0], x[1], x[2], 0.0f);
        const float n0 = fmaf(a0.x, x[0], fmaf(a0.y, x[1], fmaf(a0.z, x[2], a2.y)));
        const float n1 = fmaf(a0.w, x[0], fmaf(a1.x, x[1], fmaf(a1.y, x[2], a2.z)));
        const float n2 = fmaf(a1.z, x[0], fmaf(a1.w, x[1], fmaf(a2.x, x[2], a2.w)));
        x[0] = n0; x[1] = n1; x[2] = n2;
    };

    L(0, qa0, qa1, qa2);
    L(1, qb0, qb1, qb2);
    L(2, qc0, qc1, qc2);
    L(3, qd0, qd1, qd2);

    for (int it = 0; it < NFC / 4; ++it) {   // 13 iterations, depth-4 prefetch
        const int s = it * 4;
        useSlot(s + 0, qa0, qa1, qa2);
        if (s + 4 < NFC) L(s + 4, qa0, qa1, qa2);
        useSlot(s + 1, qb0, qb1, qb2);
        if (s + 5 < NFC) L(s + 5, qb0, qb1, qb2);
        useSlot(s + 2, qc0, qc1, qc2);
        if (s + 6 < NFC) L(s + 6, qc0, qc1, qc2);
        useSlot(s + 3, qd0, qd1, qd2);
        if (s + 7 < NFC) L(s + 7, qd0, qd1, qd2);
    }

    // boundary for the tail wave: x_{2496}
    tp0[(size_t)NFC * cs] = make_float4(x[0], x[1], x[2], 0.0f);
}

__global__ __launch_bounds__(64)
void sde_replay(const float* __restrict__ A,
                const float* __restrict__ bv,
                const float* __restrict__ C,
                const float* __restrict__ dv,
                const float* __restrict__ noise,
                const float* __restrict__ trans,
                float* __restrict__ out)
{
    __shared__ float tile[96][66];   // rolling 32-state window: row = (j&31)*3+comp

    const int lane = threadIdx.x & 63;
    const int pg   = blockIdx.x & 63;   // path group
    const int c    = blockIdx.x >> 6;   // chunk 0..52
    const int b    = (pg << 6) | lane;
    const int phi  = (11 * lane) & 15;  // own path's alignment phase

    const float dt  = 0.002f;
    const float sdt = sqrtf(dt);

    float Adt[3][3], Cs[3][3], bdt[3], dsv[3];
#pragma unroll
    for (int i = 0; i < 3; ++i) {
        bdt[i] = bv[i] * dt;
        dsv[i] = dv[i] * sdt;
#pragma unroll
        for (int j = 0; j < 3; ++j) {
            Adt[i][j] = A[i * 3 + j] * dt;
            Cs[i][j]  = C[i * 3 + j] * sdt;
        }
    }

    const float4 xb = *(const float4*)(trans + ((size_t)c * B_N + b) * 12);
    float x0r = xb.x, x1r = xb.y, x2r = xb.z;

    const float* __restrict__ nb0 = noise + (size_t)b * 3;
    const size_t nstride = (size_t)B_N * 3;
    const int base48 = c * CL;

    auto stepf = [&](float e0, float e1, float e2) {
        const float a0 = fmaf(Adt[0][2], x2r, fmaf(Adt[0][1], x1r, fmaf(Adt[0][0], x0r, bdt[0])));
        const float a1 = fmaf(Adt[1][2], x2r, fmaf(Adt[1][1], x1r, fmaf(Adt[1][0], x0r, bdt[1])));
        const float a2 = fmaf(Adt[2][2], x2r, fmaf(Adt[2][1], x1r, fmaf(Adt[2][0], x0r, bdt[2])));

        const float c0 = fmaf(Cs[0][2], x2r, fmaf(Cs[0][1], x1r, fmaf(Cs[0][0], x0r, dsv[0])));
        const float c1 = fmaf(Cs[1][2], x2r, fmaf(Cs[1][1], x1r, fmaf(Cs[1][0], x0r, dsv[1])));
        const float c2 = fmaf(Cs[2][2], x2r, fmaf(Cs[2][1], x1r, fmaf(Cs[2][0], x0r, dsv[2])));

        x0r = fmaf(c0, e0, x0r + a0);
        x1r = fmaf(c1, e1, x1r + a1);
        x2r = fmaf(c2, e2, x2r + a2);
    };

    if (c == NFC) {
        // tail wave: path p writes states [2496+phi, 2501) (only phi<=4 has any)
        float* op = out + (size_t)b * ROWF;
        if (phi == 0) {
            op[2496 * 3 + 0] = x0r; op[2496 * 3 + 1] = x1r; op[2496 * 3 + 2] = x2r;
        }
#pragma unroll
        for (int k = 0; k < 4; ++k) {
            const float* p = nb0 + (size_t)(2496 + k) * nstride;
            stepf(p[0], p[1], p[2]);
            const int j = k + 1;
            if (j >= phi) {
                float* d = op + (size_t)(2496 + j) * 3;
                d[0] = x0r; d[1] = x1r; d[2] = x2r;
            }
        }
        return;
    }

    const bool c0   = (c == 0);
    const bool last = (c == NFC - 1);

    // LDS helpers -----------------------------------------------------------
    auto tileWrite = [&](int j) {   // j compile-time in all uses
        const int r = (j & 31) * 3;
        tile[r + 0][lane] = x0r;
        tile[r + 1][lane] = x1r;
        tile[r + 2][lane] = x2r;
    };

    auto rawGuard = [&]() {   // tile writes visible before cross-lane reads
        asm volatile("s_waitcnt lgkmcnt(0)" ::: "memory");
        __builtin_amdgcn_sched_barrier(0);
    };
    auto warGuard = [&]() {   // prior flush's ds_reads done before row reuse
        asm volatile("s_waitcnt lgkmcnt(0)" ::: "memory");
        __builtin_amdgcn_sched_barrier(0);
    };

    // store roles: quad-group h=lane>>4 serves paths P=4i+h; m=lane&15 is the
    // triple index within the 192 B (16-state) aligned segment.
    const int h   = lane >> 4;
    const int m   = lane & 15;
    const int phh = (11 * h) & 15;
    float* const outG = out + (size_t)(pg << 6) * ROWF + (size_t)base48 * 3;

    auto flush = [&](auto fc, bool maskTail) {
        constexpr int F = decltype(fc)::value;
        rawGuard();
#pragma unroll
        for (int i = 0; i < 16; ++i) {
            const int P    = 4 * i + h;
            const int phiP = (12 * i + phh) & 15;   // (11*(4i+h)) & 15
            const int j    = phiP + 16 * F + m;     // local state index
            const int r    = (j & 31) * 3;
            const float v0 = tile[r + 0][P];
            const float v1 = tile[r + 1][P];
            const float v2 = tile[r + 2][P];
            if (!maskTail || (phiP + m) <= 20) {    // t = 2448+j <= 2500
                float* d = outG + (size_t)P * ROWF + (size_t)j * 3;
                d[0] = v0; d[1] = v1; d[2] = v2;
            }
        }
    };

    // noise loads (clamped for c=51 overrun; garbage states are store-masked)
    float bufA[16][3], bufB[16][3];
    auto loadN = [&](float (&buf)[16][3], int kbase, auto cnt) {
        constexpr int CNT = decltype(cnt)::value;
#pragma unroll
        for (int k = 0; k < CNT; ++k) {
            int g = base48 + kbase + k;
            g = g > (T_N - 1) ? (T_N - 1) : g;
            const float* p = nb0 + (size_t)g * nstride;
            buf[k][0] = p[0];
            buf[k][1] = p[1];
            buf[k][2] = p[2];
        }
    };

    loadN(bufA, 0,  ic<16>{});   // eps k=0..15
    loadN(bufB, 16, ic<16>{});   // eps k=16..31

    // boundary state j=0 (row 0); head states for c==0
    tileWrite(0);
    if (c0 && phi > 0) {
        float* d = outG + (size_t)lane * ROWF;   // own path, t=48c+0
        d[0] = x0r; d[1] = x1r; d[2] = x2r;
    }

    // P1: k=0..15 -> states 1..16
#pragma unroll
    for (int k = 0; k < 16; ++k) {
        stepf(bufA[k][0], bufA[k][1], bufA[k][2]);
        tileWrite(k + 1);
        if (c0 && (k + 1) < phi) {
            float* d = outG + (size_t)lane * ROWF + (size_t)(k + 1) * 3;
            d[0] = x0r; d[1] = x1r; d[2] = x2r;
        }
    }
    loadN(bufA, 32, ic<16>{});   // eps k=32..47

    // P2: k=16..30 -> states 17..31
#pragma unroll
    for (int k = 0; k < 15; ++k) {
        stepf(bufB[k][0], bufB[k][1], bufB[k][2]);
        tileWrite(k + 17);
    }
    loadN(bufB, 48, ic<14>{});   // eps k=48..61 (into bufB[0..13]; bufB[15] preserved)

    flush(ic<0>{}, false);       // segments [phi, phi+16)

    // P3: k=31 (bufB[15]) -> state 32 ; k=32..46 (bufA[0..14]) -> 33..47
    warGuard();
    stepf(bufB[15][0], bufB[15][1], bufB[15][2]);
    tileWrite(32);
#pragma unroll
    for (int k = 0; k < 15; ++k) {
        stepf(bufA[k][0], bufA[k][1], bufA[k][2]);
        tileWrite(33 + k);
    }

    flush(ic<1>{}, false);       // segments [phi+16, phi+32)

    // P4: k=47 (bufA[15]) -> state 48 ; k=48..61 (bufB[0..13]) -> 49..62
    warGuard();
    stepf(bufA[15][0], bufA[15][1], bufA[15][2]);
    tileWrite(48);
#pragma unroll
    for (int k = 0; k < 14; ++k) {
        stepf(bufB[k][0], bufB[k][1], bufB[k][2]);
        tileWrite(49 + k);
    }

    flush(ic<2>{}, last);        // segments [phi+32, phi+48), masked at t>2500
}

extern "C" void kernel_launch(void* const* d_in, const int* in_sizes, int n_in,
                              void* d_out, int out_size, void* d_ws, size_t ws_size,
                              hipStream_t stream) {
    const float* x0    = (const float*)d_in[0];
    const float* A     = (const float*)d_in[1];
    const float* bv    = (const float*)d_in[2];
    const float* C     = (const float*)d_in[3];
    const float* dv    = (const float*)d_in[4];
    const float* noise = (const float*)d_in[5];
    float* out = (float*)d_out;

    float* trans = (float*)d_ws;   // 10.42 MB

    dim3 gridPC(B_N / 64, NFC);

    sde_chunk_transforms<<<gridPC, 64, 0, stream>>>(A, bv, C, dv, noise, trans);
    sde_scan<<<B_N / 64, 64, 0, stream>>>(x0, trans);
    sde_replay<<<64 * NCH, 64, 0, stream>>>(A, bv, C, dv, noise, trans, out);
}

// Round 11
// 81.163 us; speedup vs baseline: 1.4083x; 1.0240x over previous
//
#include <hip/hip_runtime.h>
#include <math.h>
#include <type_traits>

// SDE Euler-Maruyama path generator — affine-scan decomposition, v11.
//   step:  x' = S_k x + t_k,  S_k = I + dt*A + diag(dW_k)*C,  t_k = dt*b + dW_k*d
// v10 + NON-TEMPORAL flush stores: every flush segment is 3 whole aligned 64B
// lines (per-path phase shift phi_p = (11p)&15), so nt stores stream full
// lines to HBM without L2/L3 allocation -> replay's output no longer evicts
// the noise phase 1 staged in L3 -> replay noise re-reads become L3 hits.

constexpr int B_N  = 4096;
constexpr int T_N  = 2500;
constexpr int CL   = 48;            // steps per chunk
constexpr int NFC  = T_N / CL;      // 52 full chunks
constexpr int NCH  = NFC + 1;       // 53 (incl. tail wave)
constexpr int FLP  = 12;            // phase-1 noise prefetch sub-chunk
constexpr int ROWF = (T_N + 1) * 3; // floats per output path row

template <int N> using ic = std::integral_constant<int, N>;
typedef float f4v __attribute__((ext_vector_type(4)));

// d_ws (floats): trans [NCH][B][12] — slots 0..51 hold (M 9, v 3); scan
// overwrites slot c's first float4 with boundary state x_{48c}, c=0..52.

__global__ __launch_bounds__(64)
void sde_chunk_transforms(const float* __restrict__ A,
                          const float* __restrict__ bv,
                          const float* __restrict__ C,
                          const float* __restrict__ dv,
                          const float* __restrict__ noise,
                          float* __restrict__ trans)
{
    const int b = blockIdx.x * 64 + threadIdx.x;
    const int c = blockIdx.y;          // 0..51

    const float dt  = 0.002f;
    const float sdt = sqrtf(dt);

    float IA[3][3], Cs[3][3], bdt[3], ds[3];
#pragma unroll
    for (int i = 0; i < 3; ++i) {
        bdt[i] = bv[i] * dt;
        ds[i]  = dv[i] * sdt;
#pragma unroll
        for (int j = 0; j < 3; ++j) {
            IA[i][j] = A[i * 3 + j] * dt + (i == j ? 1.0f : 0.0f);
            Cs[i][j] = C[i * 3 + j] * sdt;
        }
    }

    float M[3][3] = {{1,0,0},{0,1,0},{0,0,1}};
    float v[3] = {0, 0, 0};

    const float* __restrict__ nb = noise + (size_t)c * CL * (B_N * 3) + (size_t)b * 3;
    const size_t nstride = (size_t)B_N * 3;

    float bufA[FLP][3], bufB[FLP][3];

    auto loadChunk = [&](float (&buf)[FLP][3], int s) {
#pragma unroll
        for (int k = 0; k < FLP; ++k) {
            const float* p = nb + ((size_t)s * FLP + k) * nstride;
            buf[k][0] = p[0];
            buf[k][1] = p[1];
            buf[k][2] = p[2];
        }
    };

    auto compChunk = [&](const float (&buf)[FLP][3]) {
#pragma unroll
        for (int k = 0; k < FLP; ++k) {
            const float e[3] = { buf[k][0], buf[k][1], buf[k][2] };
            float S[3][3], t[3];
#pragma unroll
            for (int i = 0; i < 3; ++i) {
                t[i] = fmaf(e[i], ds[i], bdt[i]);
#pragma unroll
                for (int j = 0; j < 3; ++j)
                    S[i][j] = fmaf(e[i], Cs[i][j], IA[i][j]);
            }
            float nM[3][3], nv[3];
#pragma unroll
            for (int i = 0; i < 3; ++i) {
#pragma unroll
                for (int j = 0; j < 3; ++j)
                    nM[i][j] = fmaf(S[i][2], M[2][j], fmaf(S[i][1], M[1][j], S[i][0] * M[0][j]));
                nv[i] = fmaf(S[i][2], v[2], fmaf(S[i][1], v[1], S[i][0] * v[0])) + t[i];
            }
#pragma unroll
            for (int i = 0; i < 3; ++i) {
                v[i] = nv[i];
#pragma unroll
                for (int j = 0; j < 3; ++j) M[i][j] = nM[i][j];
            }
        }
    };

    loadChunk(bufA, 0);
    loadChunk(bufB, 1);
    compChunk(bufA);
    loadChunk(bufA, 2);
    compChunk(bufB);
    loadChunk(bufB, 3);
    compChunk(bufA);
    compChunk(bufB);

    float* tp = trans + ((size_t)c * B_N + b) * 12;
    float4 w0 = { M[0][0], M[0][1], M[0][2], M[1][0] };
    float4 w1 = { M[1][1], M[1][2], M[2][0], M[2][1] };
    float4 w2 = { M[2][2], v[0],    v[1],    v[2]    };
    ((float4*)tp)[0] = w0;
    ((float4*)tp)[1] = w1;
    ((float4*)tp)[2] = w2;
}

__global__ __launch_bounds__(64)
void sde_scan(const float* __restrict__ x0,
              float* __restrict__ trans)
{
    const int b = blockIdx.x * 64 + threadIdx.x;

    float x[3] = { x0[b * 3 + 0], x0[b * 3 + 1], x0[b * 3 + 2] };

    float4* tp0 = (float4*)(trans + (size_t)b * 12);
    const size_t cs = (size_t)B_N * 3;   // float4 stride between chunk slots

    float4 qa0, qa1, qa2, qb0, qb1, qb2, qc0, qc1, qc2, qd0, qd1, qd2;

    auto L = [&](int s, float4& r0, float4& r1, float4& r2) {
        const float4* tn = tp0 + (size_t)s * cs;
        r0 = tn[0]; r1 = tn[1]; r2 = tn[2];
    };
    auto useSlot = [&](int s, const float4& a0, const float4& a1, const float4& a2) {
        // overwrite slot (already consumed) with boundary state x_{48s}
        tp0[(size_t)s * cs] = make_float4(x[0], x[1], x[2], 0.0f);
        const float n0 = fmaf(a0.x, x[0], fmaf(a0.y, x[1], fmaf(a0.z, x[2], a2.y)));
        const float n1 = fmaf(a0.w, x[0], fmaf(a1.x, x[1], fmaf(a1.y, x[2], a2.z)));
        const float n2 = fmaf(a1.z, x[0], fmaf(a1.w, x[1], fmaf(a2.x, x[2], a2.w)));
        x[0] = n0; x[1] = n1; x[2] = n2;
    };

    L(0, qa0, qa1, qa2);
    L(1, qb0, qb1, qb2);
    L(2, qc0, qc1, qc2);
    L(3, qd0, qd1, qd2);

    for (int it = 0; it < NFC / 4; ++it) {   // 13 iterations, depth-4 prefetch
        const int s = it * 4;
        useSlot(s + 0, qa0, qa1, qa2);
        if (s + 4 < NFC) L(s + 4, qa0, qa1, qa2);
        useSlot(s + 1, qb0, qb1, qb2);
        if (s + 5 < NFC) L(s + 5, qb0, qb1, qb2);
        useSlot(s + 2, qc0, qc1, qc2);
        if (s + 6 < NFC) L(s + 6, qc0, qc1, qc2);
        useSlot(s + 3, qd0, qd1, qd2);
        if (s + 7 < NFC) L(s + 7, qd0, qd1, qd2);
    }

    // boundary for the tail wave: x_{2496}
    tp0[(size_t)NFC * cs] = make_float4(x[0], x[1], x[2], 0.0f);
}

__global__ __launch_bounds__(64)
void sde_replay(const float* __restrict__ A,
                const float* __restrict__ bv,
                const float* __restrict__ C,
                const float* __restrict__ dv,
                const float* __restrict__ noise,
                const float* __restrict__ trans,
                float* __restrict__ out)
{
    __shared__ float tile[96][66];   // rolling 32-state window: row = (j&31)*3+comp

    const int lane = threadIdx.x & 63;
    const int pg   = blockIdx.x & 63;   // path group
    const int c    = blockIdx.x >> 6;   // chunk 0..52
    const int b    = (pg << 6) | lane;
    const int phi  = (11 * lane) & 15;  // own path's alignment phase

    const float dt  = 0.002f;
    const float sdt = sqrtf(dt);

    float Adt[3][3], Cs[3][3], bdt[3], dsv[3];
#pragma unroll
    for (int i = 0; i < 3; ++i) {
        bdt[i] = bv[i] * dt;
        dsv[i] = dv[i] * sdt;
#pragma unroll
        for (int j = 0; j < 3; ++j) {
            Adt[i][j] = A[i * 3 + j] * dt;
            Cs[i][j]  = C[i * 3 + j] * sdt;
        }
    }

    const f4v xb = __builtin_nontemporal_load(
        (const f4v*)(trans + ((size_t)c * B_N + b) * 12));
    float x0r = xb.x, x1r = xb.y, x2r = xb.z;

    const float* __restrict__ nb0 = noise + (size_t)b * 3;
    const size_t nstride = (size_t)B_N * 3;
    const int base48 = c * CL;

    auto stepf = [&](float e0, float e1, float e2) {
        const float a0 = fmaf(Adt[0][2], x2r, fmaf(Adt[0][1], x1r, fmaf(Adt[0][0], x0r, bdt[0])));
        const float a1 = fmaf(Adt[1][2], x2r, fmaf(Adt[1][1], x1r, fmaf(Adt[1][0], x0r, bdt[1])));
        const float a2 = fmaf(Adt[2][2], x2r, fmaf(Adt[2][1], x1r, fmaf(Adt[2][0], x0r, bdt[2])));

        const float c0 = fmaf(Cs[0][2], x2r, fmaf(Cs[0][1], x1r, fmaf(Cs[0][0], x0r, dsv[0])));
        const float c1 = fmaf(Cs[1][2], x2r, fmaf(Cs[1][1], x1r, fmaf(Cs[1][0], x0r, dsv[1])));
        const float c2 = fmaf(Cs[2][2], x2r, fmaf(Cs[2][1], x1r, fmaf(Cs[2][0], x0r, dsv[2])));

        x0r = fmaf(c0, e0, x0r + a0);
        x1r = fmaf(c1, e1, x1r + a1);
        x2r = fmaf(c2, e2, x2r + a2);
    };

    if (c == NFC) {
        // tail wave: path p writes states [2496+phi, 2501) (only phi<=4 has any)
        float* op = out + (size_t)b * ROWF;
        if (phi == 0) {
            op[2496 * 3 + 0] = x0r; op[2496 * 3 + 1] = x1r; op[2496 * 3 + 2] = x2r;
        }
#pragma unroll
        for (int k = 0; k < 4; ++k) {
            const float* p = nb0 + (size_t)(2496 + k) * nstride;
            stepf(p[0], p[1], p[2]);
            const int j = k + 1;
            if (j >= phi) {
                float* d = op + (size_t)(2496 + j) * 3;
                d[0] = x0r; d[1] = x1r; d[2] = x2r;
            }
        }
        return;
    }

    const bool c0   = (c == 0);
    const bool last = (c == NFC - 1);

    // LDS helpers -----------------------------------------------------------
    auto tileWrite = [&](int j) {   // j compile-time in all uses
        const int r = (j & 31) * 3;
        tile[r + 0][lane] = x0r;
        tile[r + 1][lane] = x1r;
        tile[r + 2][lane] = x2r;
    };

    auto rawGuard = [&]() {   // tile writes visible before cross-lane reads
        asm volatile("s_waitcnt lgkmcnt(0)" ::: "memory");
        __builtin_amdgcn_sched_barrier(0);
    };
    auto warGuard = [&]() {   // prior flush's ds_reads done before row reuse
        asm volatile("s_waitcnt lgkmcnt(0)" ::: "memory");
        __builtin_amdgcn_sched_barrier(0);
    };

    // store roles: quad-group h=lane>>4 serves paths P=4i+h; m=lane&15 is the
    // triple index within the 192 B (16-state) aligned segment.
    const int h   = lane >> 4;
    const int m   = lane & 15;
    const int phh = (11 * h) & 15;
    float* const outG = out + (size_t)(pg << 6) * ROWF + (size_t)base48 * 3;

    auto flush = [&](auto fc, bool maskTail) {
        constexpr int F = decltype(fc)::value;
        rawGuard();
#pragma unroll
        for (int i = 0; i < 16; ++i) {
            const int P    = 4 * i + h;
            const int phiP = (12 * i + phh) & 15;   // (11*(4i+h)) & 15
            const int j    = phiP + 16 * F + m;     // local state index
            const int r    = (j & 31) * 3;
            const float v0 = tile[r + 0][P];
            const float v1 = tile[r + 1][P];
            const float v2 = tile[r + 2][P];
            if (!maskTail || (phiP + m) <= 20) {    // t = 2448+j <= 2500
                float* d = outG + (size_t)P * ROWF + (size_t)j * 3;
                __builtin_nontemporal_store(v0, d + 0);
                __builtin_nontemporal_store(v1, d + 1);
                __builtin_nontemporal_store(v2, d + 2);
            }
        }
    };

    // noise loads (clamped for c=51 overrun; garbage states are store-masked)
    float bufA[16][3], bufB[16][3];
    auto loadN = [&](float (&buf)[16][3], int kbase, auto cnt) {
        constexpr int CNT = decltype(cnt)::value;
#pragma unroll
        for (int k = 0; k < CNT; ++k) {
            int g = base48 + kbase + k;
            g = g > (T_N - 1) ? (T_N - 1) : g;
            const float* p = nb0 + (size_t)g * nstride;
            buf[k][0] = p[0];
            buf[k][1] = p[1];
            buf[k][2] = p[2];
        }
    };

    loadN(bufA, 0,  ic<16>{});   // eps k=0..15
    loadN(bufB, 16, ic<16>{});   // eps k=16..31

    // boundary state j=0 (row 0); head states for c==0
    tileWrite(0);
    if (c0 && phi > 0) {
        float* d = outG + (size_t)lane * ROWF;   // own path, t=0
        d[0] = x0r; d[1] = x1r; d[2] = x2r;
    }

    // P1: k=0..15 -> states 1..16
#pragma unroll
    for (int k = 0; k < 16; ++k) {
        stepf(bufA[k][0], bufA[k][1], bufA[k][2]);
        tileWrite(k + 1);
        if (c0 && (k + 1) < phi) {
            float* d = outG + (size_t)lane * ROWF + (size_t)(k + 1) * 3;
            d[0] = x0r; d[1] = x1r; d[2] = x2r;
        }
    }
    loadN(bufA, 32, ic<16>{});   // eps k=32..47

    // P2: k=16..30 -> states 17..31
#pragma unroll
    for (int k = 0; k < 15; ++k) {
        stepf(bufB[k][0], bufB[k][1], bufB[k][2]);
        tileWrite(k + 17);
    }
    loadN(bufB, 48, ic<14>{});   // eps k=48..61 (into bufB[0..13]; bufB[15] preserved)

    flush(ic<0>{}, false);       // segments [phi, phi+16)

    // P3: k=31 (bufB[15]) -> state 32 ; k=32..46 (bufA[0..14]) -> 33..47
    warGuard();
    stepf(bufB[15][0], bufB[15][1], bufB[15][2]);
    tileWrite(32);
#pragma unroll
    for (int k = 0; k < 15; ++k) {
        stepf(bufA[k][0], bufA[k][1], bufA[k][2]);
        tileWrite(33 + k);
    }

    flush(ic<1>{}, false);       // segments [phi+16, phi+32)

    // P4: k=47 (bufA[15]) -> state 48 ; k=48..61 (bufB[0..13]) -> 49..62
    warGuard();
    stepf(bufA[15][0], bufA[15][1], bufA[15][2]);
    tileWrite(48);
#pragma unroll
    for (int k = 0; k < 14; ++k) {
        stepf(bufB[k][0], bufB[k][1], bufB[k][2]);
        tileWrite(49 + k);
    }

    flush(ic<2>{}, last);        // segments [phi+32, phi+48), masked at t>2500
}

extern "C" void kernel_launch(void* const* d_in, const int* in_sizes, int n_in,
                              void* d_out, int out_size, void* d_ws, size_t ws_size,
                              hipStream_t stream) {
    const float* x0    = (const float*)d_in[0];
    const float* A     = (const float*)d_in[1];
    const float* bv    = (const float*)d_in[2];
    const float* C     = (const float*)d_in[3];
    const float* dv    = (const float*)d_in[4];
    const float* noise = (const float*)d_in[5];
    float* out = (float*)d_out;

    float* trans = (float*)d_ws;   // 10.42 MB

    dim3 gridPC(B_N / 64, NFC);

    sde_chunk_transforms<<<gridPC, 64, 0, stream>>>(A, bv, C, dv, noise, trans);
    sde_scan<<<B_N / 64, 64, 0, stream>>>(x0, trans);
    sde_replay<<<64 * NCH, 64, 0, stream>>>(A, bv, C, dv, noise, trans, out);
}

// Round 12
// 80.895 us; speedup vs baseline: 1.4130x; 1.0033x over previous
//
#include <hip/hip_runtime.h>
#include <math.h>
#include <type_traits>

// SDE Euler-Maruyama path generator — affine-scan decomposition, v12.
//   step:  x' = S_k x + t_k,  S_k = I + dt*A + diag(dW_k)*C,  t_k = dt*b + dW_k*d
// v11 (phi-phase aligned full-line nt stores, rolling-32 LDS window) with:
//   - CL=64 chunks: noise re-read overlap 79/64 = 1.23x (was 62/48 = 1.29x)
//   - replay chunk order REVERSED: phase 1 leaves high chunks freshest in the
//     MALL; replay consumes descending -> newest-first, LRU-friendly.

constexpr int B_N  = 4096;
constexpr int T_N  = 2500;
constexpr int CL   = 64;            // steps per chunk (64c == 0 mod 16: phase math holds)
constexpr int NFC  = T_N / CL;      // 39 full chunks (2496 steps)
constexpr int NCH  = NFC + 1;       // 40 (incl. tail wave)
constexpr int FLP  = 8;             // phase-1 noise prefetch sub-chunk
constexpr int ROWF = (T_N + 1) * 3; // floats per output path row

template <int N> using ic = std::integral_constant<int, N>;
typedef float f4v __attribute__((ext_vector_type(4)));

// d_ws (floats): trans [NCH][B][12] — slots 0..38 hold (M 9, v 3); scan
// overwrites slot c's first float4 with boundary state x_{64c}, c=0..39.

__global__ __launch_bounds__(64)
void sde_chunk_transforms(const float* __restrict__ A,
                          const float* __restrict__ bv,
                          const float* __restrict__ C,
                          const float* __restrict__ dv,
                          const float* __restrict__ noise,
                          float* __restrict__ trans)
{
    const int b = blockIdx.x * 64 + threadIdx.x;
    const int c = blockIdx.y;          // 0..38

    const float dt  = 0.002f;
    const float sdt = sqrtf(dt);

    float IA[3][3], Cs[3][3], bdt[3], ds[3];
#pragma unroll
    for (int i = 0; i < 3; ++i) {
        bdt[i] = bv[i] * dt;
        ds[i]  = dv[i] * sdt;
#pragma unroll
        for (int j = 0; j < 3; ++j) {
            IA[i][j] = A[i * 3 + j] * dt + (i == j ? 1.0f : 0.0f);
            Cs[i][j] = C[i * 3 + j] * sdt;
        }
    }

    float M[3][3] = {{1,0,0},{0,1,0},{0,0,1}};
    float v[3] = {0, 0, 0};

    const float* __restrict__ nb = noise + (size_t)c * CL * (B_N * 3) + (size_t)b * 3;
    const size_t nstride = (size_t)B_N * 3;

    float bufA[FLP][3], bufB[FLP][3];

    auto loadChunk = [&](float (&buf)[FLP][3], int s) {
#pragma unroll
        for (int k = 0; k < FLP; ++k) {
            const float* p = nb + ((size_t)s * FLP + k) * nstride;
            buf[k][0] = p[0];
            buf[k][1] = p[1];
            buf[k][2] = p[2];
        }
    };

    auto compChunk = [&](const float (&buf)[FLP][3]) {
#pragma unroll
        for (int k = 0; k < FLP; ++k) {
            const float e[3] = { buf[k][0], buf[k][1], buf[k][2] };
            float S[3][3], t[3];
#pragma unroll
            for (int i = 0; i < 3; ++i) {
                t[i] = fmaf(e[i], ds[i], bdt[i]);
#pragma unroll
                for (int j = 0; j < 3; ++j)
                    S[i][j] = fmaf(e[i], Cs[i][j], IA[i][j]);
            }
            float nM[3][3], nv[3];
#pragma unroll
            for (int i = 0; i < 3; ++i) {
#pragma unroll
                for (int j = 0; j < 3; ++j)
                    nM[i][j] = fmaf(S[i][2], M[2][j], fmaf(S[i][1], M[1][j], S[i][0] * M[0][j]));
                nv[i] = fmaf(S[i][2], v[2], fmaf(S[i][1], v[1], S[i][0] * v[0])) + t[i];
            }
#pragma unroll
            for (int i = 0; i < 3; ++i) {
                v[i] = nv[i];
#pragma unroll
                for (int j = 0; j < 3; ++j) M[i][j] = nM[i][j];
            }
        }
    };

    // CL/FLP = 8 sub-chunks, double-buffered
    loadChunk(bufA, 0);
    loadChunk(bufB, 1);
    compChunk(bufA); loadChunk(bufA, 2);
    compChunk(bufB); loadChunk(bufB, 3);
    compChunk(bufA); loadChunk(bufA, 4);
    compChunk(bufB); loadChunk(bufB, 5);
    compChunk(bufA); loadChunk(bufA, 6);
    compChunk(bufB); loadChunk(bufB, 7);
    compChunk(bufA);
    compChunk(bufB);

    float* tp = trans + ((size_t)c * B_N + b) * 12;
    float4 w0 = { M[0][0], M[0][1], M[0][2], M[1][0] };
    float4 w1 = { M[1][1], M[1][2], M[2][0], M[2][1] };
    float4 w2 = { M[2][2], v[0],    v[1],    v[2]    };
    ((float4*)tp)[0] = w0;
    ((float4*)tp)[1] = w1;
    ((float4*)tp)[2] = w2;
}

__global__ __launch_bounds__(64)
void sde_scan(const float* __restrict__ x0,
              float* __restrict__ trans)
{
    const int b = blockIdx.x * 64 + threadIdx.x;

    float x[3] = { x0[b * 3 + 0], x0[b * 3 + 1], x0[b * 3 + 2] };

    float4* tp0 = (float4*)(trans + (size_t)b * 12);
    const size_t cs = (size_t)B_N * 3;   // float4 stride between chunk slots

    float4 qa0, qa1, qa2, qb0, qb1, qb2, qc0, qc1, qc2, qd0, qd1, qd2;

    auto L = [&](int s, float4& r0, float4& r1, float4& r2) {
        const float4* tn = tp0 + (size_t)s * cs;
        r0 = tn[0]; r1 = tn[1]; r2 = tn[2];
    };
    auto useSlot = [&](int s, const float4& a0, const float4& a1, const float4& a2) {
        // overwrite slot (already consumed) with boundary state x_{64s}
        tp0[(size_t)s * cs] = make_float4(x[0], x[1], x[2], 0.0f);
        const float n0 = fmaf(a0.x, x[0], fmaf(a0.y, x[1], fmaf(a0.z, x[2], a2.y)));
        const float n1 = fmaf(a0.w, x[0], fmaf(a1.x, x[1], fmaf(a1.y, x[2], a2.z)));
        const float n2 = fmaf(a1.z, x[0], fmaf(a1.w, x[1], fmaf(a2.x, x[2], a2.w)));
        x[0] = n0; x[1] = n1; x[2] = n2;
    };

    L(0, qa0, qa1, qa2);
    L(1, qb0, qb1, qb2);
    L(2, qc0, qc1, qc2);
    L(3, qd0, qd1, qd2);

    for (int it = 0; it < 9; ++it) {     // slots 0..35, depth-4 prefetch
        const int s = it * 4;
        useSlot(s + 0, qa0, qa1, qa2);
        if (s + 4 < NFC) L(s + 4, qa0, qa1, qa2);
        useSlot(s + 1, qb0, qb1, qb2);
        if (s + 5 < NFC) L(s + 5, qb0, qb1, qb2);
        useSlot(s + 2, qc0, qc1, qc2);
        if (s + 6 < NFC) L(s + 6, qc0, qc1, qc2);
        useSlot(s + 3, qd0, qd1, qd2);
        if (s + 7 < NFC) L(s + 7, qd0, qd1, qd2);
    }
    useSlot(36, qa0, qa1, qa2);          // remainder 36,37,38
    useSlot(37, qb0, qb1, qb2);
    useSlot(38, qc0, qc1, qc2);

    // boundary for the tail wave: x_{2496}
    tp0[(size_t)NFC * cs] = make_float4(x[0], x[1], x[2], 0.0f);
}

__global__ __launch_bounds__(64)
void sde_replay(const float* __restrict__ A,
                const float* __restrict__ bv,
                const float* __restrict__ C,
                const float* __restrict__ dv,
                const float* __restrict__ noise,
                const float* __restrict__ trans,
                float* __restrict__ out)
{
    __shared__ float tile[96][66];   // rolling 32-state window: row = (j&31)*3+comp

    const int lane = threadIdx.x & 63;
    const int pg   = blockIdx.x & 63;              // path group
    const int c    = (NCH - 1) - (blockIdx.x >> 6); // REVERSED: 39(tail)..0
    const int b    = (pg << 6) | lane;
    const int phi  = (11 * lane) & 15;             // own path's alignment phase

    const float dt  = 0.002f;
    const float sdt = sqrtf(dt);

    float Adt[3][3], Cs[3][3], bdt[3], dsv[3];
#pragma unroll
    for (int i = 0; i < 3; ++i) {
        bdt[i] = bv[i] * dt;
        dsv[i] = dv[i] * sdt;
#pragma unroll
        for (int j = 0; j < 3; ++j) {
            Adt[i][j] = A[i * 3 + j] * dt;
            Cs[i][j]  = C[i * 3 + j] * sdt;
        }
    }

    const f4v xb = __builtin_nontemporal_load(
        (const f4v*)(trans + ((size_t)c * B_N + b) * 12));
    float x0r = xb.x, x1r = xb.y, x2r = xb.z;

    const float* __restrict__ nb0 = noise + (size_t)b * 3;
    const size_t nstride = (size_t)B_N * 3;
    const int base = c * CL;

    auto stepf = [&](float e0, float e1, float e2) {
        const float a0 = fmaf(Adt[0][2], x2r, fmaf(Adt[0][1], x1r, fmaf(Adt[0][0], x0r, bdt[0])));
        const float a1 = fmaf(Adt[1][2], x2r, fmaf(Adt[1][1], x1r, fmaf(Adt[1][0], x0r, bdt[1])));
        const float a2 = fmaf(Adt[2][2], x2r, fmaf(Adt[2][1], x1r, fmaf(Adt[2][0], x0r, bdt[2])));

        const float c0 = fmaf(Cs[0][2], x2r, fmaf(Cs[0][1], x1r, fmaf(Cs[0][0], x0r, dsv[0])));
        const float c1 = fmaf(Cs[1][2], x2r, fmaf(Cs[1][1], x1r, fmaf(Cs[1][0], x0r, dsv[1])));
        const float c2 = fmaf(Cs[2][2], x2r, fmaf(Cs[2][1], x1r, fmaf(Cs[2][0], x0r, dsv[2])));

        x0r = fmaf(c0, e0, x0r + a0);
        x1r = fmaf(c1, e1, x1r + a1);
        x2r = fmaf(c2, e2, x2r + a2);
    };

    if (c == NFC) {
        // tail wave: path p writes states [2496+phi, 2501) (only phi<=4 has any)
        float* op = out + (size_t)b * ROWF;
        if (phi == 0) {
            op[2496 * 3 + 0] = x0r; op[2496 * 3 + 1] = x1r; op[2496 * 3 + 2] = x2r;
        }
#pragma unroll
        for (int k = 0; k < 4; ++k) {
            const float* p = nb0 + (size_t)(2496 + k) * nstride;
            stepf(p[0], p[1], p[2]);
            const int j = k + 1;
            if (j >= phi) {
                float* d = op + (size_t)(2496 + j) * 3;
                d[0] = x0r; d[1] = x1r; d[2] = x2r;
            }
        }
        return;
    }

    const bool c0   = (c == 0);
    const bool last = (c == NFC - 1);

    // LDS helpers -----------------------------------------------------------
    auto tileWrite = [&](int j) {   // j compile-time in all uses
        const int r = (j & 31) * 3;
        tile[r + 0][lane] = x0r;
        tile[r + 1][lane] = x1r;
        tile[r + 2][lane] = x2r;
    };

    auto rawGuard = [&]() {   // tile writes visible before cross-lane reads
        asm volatile("s_waitcnt lgkmcnt(0)" ::: "memory");
        __builtin_amdgcn_sched_barrier(0);
    };
    auto warGuard = [&]() {   // prior flush's ds_reads done before row reuse
        asm volatile("s_waitcnt lgkmcnt(0)" ::: "memory");
        __builtin_amdgcn_sched_barrier(0);
    };

    // store roles: quad-group h=lane>>4 serves paths P=4i+h; m=lane&15 is the
    // triple index within the 192 B (16-state) aligned segment.
    const int h   = lane >> 4;
    const int m   = lane & 15;
    const int phh = (11 * h) & 15;
    float* const outG = out + (size_t)(pg << 6) * ROWF + (size_t)base * 3;

    auto flush = [&](auto fc, bool maskTail) {
        constexpr int F = decltype(fc)::value;
        rawGuard();
#pragma unroll
        for (int i = 0; i < 16; ++i) {
            const int P    = 4 * i + h;
            const int phiP = (12 * i + phh) & 15;   // (11*(4i+h)) & 15
            const int j    = phiP + 16 * F + m;     // local state index
            const int r    = (j & 31) * 3;
            const float v0 = tile[r + 0][P];
            const float v1 = tile[r + 1][P];
            const float v2 = tile[r + 2][P];
            if (!maskTail || (phiP + m) <= 20) {    // t = 2432+j <= 2500
                float* d = outG + (size_t)P * ROWF + (size_t)j * 3;
                __builtin_nontemporal_store(v0, d + 0);
                __builtin_nontemporal_store(v1, d + 1);
                __builtin_nontemporal_store(v2, d + 2);
            }
        }
    };

    // noise loads (clamped for c=38 overrun; garbage states are store-masked)
    float bufA[16][3], bufB[16][3];
    auto loadN = [&](float (&buf)[16][3], int kbase, auto cnt) {
        constexpr int CNT = decltype(cnt)::value;
#pragma unroll
        for (int k = 0; k < CNT; ++k) {
            int g = base + kbase + k;
            g = g > (T_N - 1) ? (T_N - 1) : g;
            const float* p = nb0 + (size_t)g * nstride;
            buf[k][0] = p[0];
            buf[k][1] = p[1];
            buf[k][2] = p[2];
        }
    };

    loadN(bufA, 0,  ic<16>{});   // eps k=0..15
    loadN(bufB, 16, ic<16>{});   // eps k=16..31

    // boundary state j=0 (row 0); head states for c==0
    tileWrite(0);
    if (c0 && phi > 0) {
        float* d = outG + (size_t)lane * ROWF;   // own path, t=0
        d[0] = x0r; d[1] = x1r; d[2] = x2r;
    }

    // P1: k=0..15 -> states 1..16
#pragma unroll
    for (int k = 0; k < 16; ++k) {
        stepf(bufA[k][0], bufA[k][1], bufA[k][2]);
        tileWrite(k + 1);
        if (c0 && (k + 1) < phi) {
            float* d = outG + (size_t)lane * ROWF + (size_t)(k + 1) * 3;
            d[0] = x0r; d[1] = x1r; d[2] = x2r;
        }
    }
    loadN(bufA, 32, ic<16>{});   // eps k=32..47

    // P2: k=16..30 -> states 17..31
#pragma unroll
    for (int k = 0; k < 15; ++k) {
        stepf(bufB[k][0], bufB[k][1], bufB[k][2]);
        tileWrite(k + 17);
    }

    flush(ic<0>{}, false);       // segments [phi, phi+16)

    // P3: k=31 (bufB[15]) -> state 32 ; then k=32..46 (bufA[0..14]) -> 33..47
    warGuard();
    stepf(bufB[15][0], bufB[15][1], bufB[15][2]);
    tileWrite(32);
    loadN(bufB, 48, ic<16>{});   // eps k=48..63 (bufB fully free now)
#pragma unroll
    for (int k = 0; k < 15; ++k) {
        stepf(bufA[k][0], bufA[k][1], bufA[k][2]);
        tileWrite(33 + k);
    }

    flush(ic<1>{}, false);       // segments [phi+16, phi+32)

    // P4: k=47 (bufA[15]) -> state 48 ; then k=48..62 (bufB[0..14]) -> 49..63
    warGuard();
    stepf(bufA[15][0], bufA[15][1], bufA[15][2]);
    tileWrite(48);
    loadN(bufA, 64, ic<15>{});   // eps k=64..78 (bufA[15] dead after this point)
#pragma unroll
    for (int k = 0; k < 15; ++k) {
        stepf(bufB[k][0], bufB[k][1], bufB[k][2]);
        tileWrite(49 + k);
    }

    flush(ic<2>{}, false);       // segments [phi+32, phi+48)

    // P5: k=63 (bufB[15]) -> state 64 ; then k=64..78 (bufA[0..14]) -> 65..79
    warGuard();
    stepf(bufB[15][0], bufB[15][1], bufB[15][2]);
    tileWrite(64);
#pragma unroll
    for (int k = 0; k < 15; ++k) {
        stepf(bufA[k][0], bufA[k][1], bufA[k][2]);
        tileWrite(65 + k);
    }

    flush(ic<3>{}, last);        // segments [phi+48, phi+64), masked at t>2500
}

extern "C" void kernel_launch(void* const* d_in, const int* in_sizes, int n_in,
                              void* d_out, int out_size, void* d_ws, size_t ws_size,
                              hipStream_t stream) {
    const float* x0    = (const float*)d_in[0];
    const float* A     = (const float*)d_in[1];
    const float* bv    = (const float*)d_in[2];
    const float* C     = (const float*)d_in[3];
    const float* dv    = (const float*)d_in[4];
    const float* noise = (const float*)d_in[5];
    float* out = (float*)d_out;

    float* trans = (float*)d_ws;   // 7.86 MB

    dim3 gridPC(B_N / 64, NFC);

    sde_chunk_transforms<<<gridPC, 64, 0, stream>>>(A, bv, C, dv, noise, trans);
    sde_scan<<<B_N / 64, 64, 0, stream>>>(x0, trans);
    sde_replay<<<64 * NCH, 64, 0, stream>>>(A, bv, C, dv, noise, trans, out);
}